// Round 1
// 111.824 us; speedup vs baseline: 1.0572x; 1.0572x over previous
//
#include <hip/hip_runtime.h>

#define NQ 9
#define NS 512            // 2^9 amplitudes
#define M2 1024           // [Re V; Im V] stacked rows
#define NSIMB 256         // sim blocks: 2 columns each (512 cols total)

#define COEF_ROT_BASE (72*32)                 // 72 ent steps x 32 floats
#define COEF_R3_BASE  (COEF_ROT_BASE + 27*8)  // + 27 rots x 8 floats
#define COEF_FLOATS   (COEF_R3_BASE + 3*128)  // + 3 merged 8x8 rot tables

typedef __attribute__((ext_vector_type(8))) short bf16x8;
typedef __attribute__((ext_vector_type(4))) float f32x4;

__device__ inline unsigned short f2bf(float f){
  unsigned int u = __float_as_uint(f);
  u += 0x7fffu + ((u >> 16) & 1u);   // round-to-nearest-even
  return (unsigned short)(u >> 16);
}

// =====================  2-wave-per-column statevector sim  =====================
// Column t: one 2-wave pair. Amp i = (wvb<<8)|(r<<6)|lane : bits0-5 lane,
// bits6-7 register r (4 amps/thread), bit8 wave. Wire w <-> bit (8-w).
// Only ops touching bit 8 need an LDS exchange round (22 rounds total, strict
// A/B ping-pong, one __syncthreads each). Everything else is reg/DPP/swizzle.

template<int LM>
__device__ inline float lxor(float v){
  if constexpr (LM == 1)
    return __int_as_float(__builtin_amdgcn_mov_dpp(__float_as_int(v), 0xB1, 0xF, 0xF, true));
  else if constexpr (LM == 2)
    return __int_as_float(__builtin_amdgcn_mov_dpp(__float_as_int(v), 0x4E, 0xF, 0xF, true));
  else if constexpr (LM == 3)
    return __int_as_float(__builtin_amdgcn_mov_dpp(__float_as_int(v), 0x1B, 0xF, 0xF, true));
  else if constexpr (LM < 32)
    return __int_as_float(__builtin_amdgcn_ds_swizzle(__float_as_int(v), (LM<<10)|0x1F));
  else
    return __shfl_xor(v, LM);
}

template<int M>
__device__ inline float lx(float v){
  if constexpr ((M & 63) == 0) return v;
  else return lxor<(M & 63)>(v);
}

// partner value for xor-mask M: reg part from (own | partner-wave) regs, lane part via lxor
template<int M>
__device__ inline void getp(const float (&ox)[4], const float (&oy)[4],
                            const float2 (&pv)[4], int r, float& qx, float& qy){
  constexpr int MR = (M >> 6) & 3;
  float vx, vy;
  if constexpr ((M & 0x100) != 0){ vx = pv[r^MR].x; vy = pv[r^MR].y; }
  else                           { vx = ox[r^MR];   vy = oy[r^MR];   }
  qx = lx<M>(vx); qy = lx<M>(vy);
}

// cross-wave exchange: publish own 4 regs, read partner wave's 4 regs (same lane)
__device__ inline void xwave(const float (&ax)[4], const float (&ay)[4],
                             int wvb, int lane, float2* xb, float2 (&pv)[4]){
  #pragma unroll
  for (int r = 0; r < 4; ++r) xb[(wvb*4+r)*64 + lane] = make_float2(ax[r], ay[r]);
  __syncthreads();
  #pragma unroll
  for (int r = 0; r < 4; ++r) pv[r] = xb[((wvb^1)*4+r)*64 + lane];
}

// fused 4x4 ent step on bit-pair (CM, TM); coefs identical layout to before
template<int CM,int TM>
__device__ inline void stepQ(float (&ax)[4], float (&ay)[4], int wvb, int lane,
                             float2* xb, const float* g){
  constexpr bool HX = ((CM | TM) & 0x100) != 0;
  float2 pv[4];
  if constexpr (HX) xwave(ax, ay, wvb, lane, xb, pv);
  float ox[4], oy[4];
  #pragma unroll
  for (int r = 0; r < 4; ++r){ ox[r] = ax[r]; oy[r] = ay[r]; }
  #pragma unroll
  for (int r = 0; r < 4; ++r){
    float tx,ty,cx,cy,bx,by;
    getp<TM>(ox, oy, pv, r, tx, ty);
    getp<CM>(ox, oy, pv, r, cx, cy);
    getp<(CM^TM)>(ox, oy, pv, r, bx, by);
    int i = (wvb << 8) | (r << 6) | lane;
    int p = ((i & CM) ? 2 : 0) | ((i & TM) ? 1 : 0);
    float4 hx = *(const float4*)(g + p*4);
    float4 hy = *(const float4*)(g + 16 + p*4);
    ax[r] = hx.x*ox[r]-hy.x*oy[r] + hx.y*tx-hy.y*ty + hx.z*cx-hy.z*cy + hx.w*bx-hy.w*by;
    ay[r] = hx.x*oy[r]+hy.x*ox[r] + hx.y*ty+hy.y*tx + hx.z*cy+hy.z*cx + hx.w*by+hy.w*bx;
  }
}

// ent block: I=0 exchanges on bufA, I=8 on bufB, I=1..7 purely in-wave
template<int I = 0>
__device__ inline void ent_blkQ(float (&ax)[4], float (&ay)[4], int wvb, int lane,
                                float2* ebA, float2* ebB, const float* S){
  if constexpr      (I == 0) stepQ<0x100,0x080>(ax, ay, wvb, lane, ebA, S);
  else if constexpr (I == 8) stepQ<0x001,0x100>(ax, ay, wvb, lane, ebB, S + 256);
  else                       stepQ<(0x100>>I),(0x080>>I)>(ax, ay, wvb, lane, ebA, S + I*32);
  if constexpr (I < 8) ent_blkQ<I+1>(ax, ay, wvb, lane, ebA, ebB, S);
}

// merged Rot(w0)xRot(w1)xRot(w2) on bits 8,7,6: one exchange round + 8 cmacs/amp
__device__ inline void rot3Q(float (&ax)[4], float (&ay)[4], int wvb, int lane,
                             float2* xb, const float* Mt){
  float2 pv[4];
  xwave(ax, ay, wvb, lane, xb, pv);
  bool w1 = (wvb != 0);
  float l0x[4],l0y[4],l1x[4],l1y[4];  // amps with wave-bit 0 / 1
  #pragma unroll
  for (int r = 0; r < 4; ++r){
    l0x[r] = w1 ? pv[r].x : ax[r];  l0y[r] = w1 ? pv[r].y : ay[r];
    l1x[r] = w1 ? ax[r]   : pv[r].x; l1y[r] = w1 ? ay[r]   : pv[r].y;
  }
  #pragma unroll
  for (int r = 0; r < 4; ++r){
    const float4* row = (const float4*)(Mt + ((wvb<<2)|r)*16);
    float4 m0 = row[0], m1 = row[1], m2 = row[2], m3 = row[3];
    float nx, ny;
    nx  = m0.x*l0x[0]-m0.y*l0y[0];  ny  = m0.x*l0y[0]+m0.y*l0x[0];
    nx += m0.z*l0x[1]-m0.w*l0y[1];  ny += m0.z*l0y[1]+m0.w*l0x[1];
    nx += m1.x*l0x[2]-m1.y*l0y[2];  ny += m1.x*l0y[2]+m1.y*l0x[2];
    nx += m1.z*l0x[3]-m1.w*l0y[3];  ny += m1.z*l0y[3]+m1.w*l0x[3];
    nx += m2.x*l1x[0]-m2.y*l1y[0];  ny += m2.x*l1y[0]+m2.y*l1x[0];
    nx += m2.z*l1x[1]-m2.w*l1y[1];  ny += m2.z*l1y[1]+m2.w*l1x[1];
    nx += m3.x*l1x[2]-m3.y*l1y[2];  ny += m3.x*l1y[2]+m3.y*l1x[2];
    nx += m3.z*l1x[3]-m3.w*l1y[3];  ny += m3.z*l1y[3]+m3.w*l1x[3];
    ax[r] = nx; ay[r] = ny;
  }
}

// Rot on a lane-bit wire
template<int LM>
__device__ inline void rotQ(float (&ax)[4], float (&ay)[4], int lane, const float* u){
  float4 uu = *(const float4*)(u + ((lane & LM) ? 4 : 0));
  #pragma unroll
  for (int r = 0; r < 4; ++r){
    float px = lxor<LM>(ax[r]), py = lxor<LM>(ay[r]);
    float nx = uu.x*ax[r]-uu.y*ay[r] + uu.z*px-uu.w*py;
    float ny = uu.x*ay[r]+uu.y*ax[r] + uu.z*py+uu.w*px;
    ax[r] = nx; ay[r] = ny;
  }
}

template<int I = 3>
__device__ inline void sel_rotsQ(float (&ax)[4], float (&ay)[4], int lane, const float* ub){
  rotQ<(1<<(8-I))>(ax, ay, lane, ub + I*8);
  if constexpr (I < 8) sel_rotsQ<I+1>(ax, ay, lane, ub);
}

// ---- CNOT primitives (new[x] = old[x ^ (control?targetbit:0)]) ----
template<int TR>  // control = wave bit, target = reg bit
__device__ inline void cn_wr(float (&ax)[4], float (&ay)[4], int wvb){
  if (wvb){
    #pragma unroll
    for (int r = 0; r < 4; ++r) if (!(r & TR)){
      float t = ax[r]; ax[r] = ax[r|TR]; ax[r|TR] = t;
      t = ay[r]; ay[r] = ay[r|TR]; ay[r|TR] = t;
    }
  }
}
template<int TL>  // control = wave bit, target = lane bit
__device__ inline void cn_wl(float (&ax)[4], float (&ay)[4], int wvb){
  if (wvb){
    #pragma unroll
    for (int r = 0; r < 4; ++r){ ax[r] = lxor<TL>(ax[r]); ay[r] = lxor<TL>(ay[r]); }
  }
}
template<int CR,int TR>  // reg control, reg target
__device__ inline void cn_rr(float (&ax)[4], float (&ay)[4]){
  #pragma unroll
  for (int r = 0; r < 4; ++r) if ((r & CR) && !(r & TR)){
    float t = ax[r]; ax[r] = ax[r|TR]; ax[r|TR] = t;
    t = ay[r]; ay[r] = ay[r|TR]; ay[r|TR] = t;
  }
}
template<int CR,int TL>  // reg control, lane target
__device__ inline void cn_rl(float (&ax)[4], float (&ay)[4]){
  #pragma unroll
  for (int r = 0; r < 4; ++r) if (r & CR){ ax[r] = lxor<TL>(ax[r]); ay[r] = lxor<TL>(ay[r]); }
}
template<int CL,int TR>  // lane control, reg target
__device__ inline void cn_lr(float (&ax)[4], float (&ay)[4], int lane){
  bool c = (lane & CL) != 0;
  #pragma unroll
  for (int r = 0; r < 4; ++r) if (!(r & TR)){
    int rp = r | TR;
    float t0x = ax[r], t0y = ay[r];
    ax[r]  = c ? ax[rp] : t0x;  ay[r]  = c ? ay[rp] : t0y;
    ax[rp] = c ? t0x : ax[rp];  ay[rp] = c ? t0y : ay[rp];
  }
}
template<int CL,int TL>  // lane control, lane target
__device__ inline void cn_ll(float (&ax)[4], float (&ay)[4], int lane){
  bool c = (lane & CL) != 0;
  #pragma unroll
  for (int r = 0; r < 4; ++r){
    float px = lxor<TL>(ax[r]), py = lxor<TL>(ay[r]);
    ax[r] = c ? px : ax[r];  ay[r] = c ? py : ay[r];
  }
}
template<int CL>  // lane control, target = wave bit (the only exchange in a ring)
__device__ inline void cn_lw(float (&ax)[4], float (&ay)[4], int wvb, int lane, float2* xb){
  float2 pv[4];
  xwave(ax, ay, wvb, lane, xb, pv);
  bool c = (lane & CL) != 0;
  #pragma unroll
  for (int r = 0; r < 4; ++r){ ax[r] = c ? pv[r].x : ax[r]; ay[r] = c ? pv[r].y : ay[r]; }
}

// CNOT rings (gate order i=0..8, wire w <-> bit 8-w), range compile-time
__device__ inline void ring1(float (&ax)[4], float (&ay)[4], int wvb, int lane, float2* xb){
  cn_wr<2>(ax,ay,wvb);        // 0->1 : bit 8 -> 7
  cn_rr<2,1>(ax,ay);          // 1->2 : 7 -> 6
  cn_rl<1,32>(ax,ay);         // 2->3 : 6 -> 5
  cn_ll<32,16>(ax,ay,lane);   // 3->4
  cn_ll<16,8>(ax,ay,lane);    // 4->5
  cn_ll<8,4>(ax,ay,lane);     // 5->6
  cn_ll<4,2>(ax,ay,lane);     // 6->7
  cn_ll<2,1>(ax,ay,lane);     // 7->8
  cn_lw<1>(ax,ay,wvb,lane,xb);// 8->0 : bit 0 -> 8
}
__device__ inline void ring2(float (&ax)[4], float (&ay)[4], int wvb, int lane, float2* xb){
  cn_wr<1>(ax,ay,wvb);        // 0->2 : 8 -> 6
  cn_rl<2,32>(ax,ay);         // 1->3 : 7 -> 5
  cn_rl<1,16>(ax,ay);         // 2->4 : 6 -> 4
  cn_ll<32,8>(ax,ay,lane);    // 3->5
  cn_ll<16,4>(ax,ay,lane);    // 4->6
  cn_ll<8,2>(ax,ay,lane);     // 5->7
  cn_ll<4,1>(ax,ay,lane);     // 6->8
  cn_lw<2>(ax,ay,wvb,lane,xb);// 7->0 : bit 1 -> 8
  cn_lr<1,2>(ax,ay,lane);     // 8->1 : bit 0 -> 7
}
__device__ inline void ring3(float (&ax)[4], float (&ay)[4], int wvb, int lane, float2* xb){
  cn_wl<32>(ax,ay,wvb);       // 0->3 : 8 -> 5
  cn_rl<2,16>(ax,ay);         // 1->4 : 7 -> 4
  cn_rl<1,8>(ax,ay);          // 2->5 : 6 -> 3
  cn_ll<32,4>(ax,ay,lane);    // 3->6
  cn_ll<16,2>(ax,ay,lane);    // 4->7
  cn_ll<8,1>(ax,ay,lane);     // 5->8
  cn_lw<4>(ax,ay,wvb,lane,xb);// 6->0 : bit 2 -> 8
  cn_lr<2,2>(ax,ay,lane);     // 7->1 : bit 1 -> 7
  cn_lr<1,1>(ax,ay,lane);     // 8->2 : bit 0 -> 6
}

// Combined kernel: blocks [0,NSIMB) simulate 2 V columns each; blocks >= NSIMB run prep.
__global__ __launch_bounds__(256) void sim_prep(const float* __restrict__ params,
                                                const float* __restrict__ weights,
                                                const float* __restrict__ params2,
                                                const float* __restrict__ adds,
                                                unsigned short* __restrict__ A2,
                                                unsigned short* __restrict__ cT,
                                                float* __restrict__ out, int B){
  int tid = threadIdx.x;

  if (blockIdx.x >= NSIMB){
    // ---- prep path: build c (wave per sample) + zero the output accumulator ----
    int gid = (blockIdx.x - NSIMB) * 256 + tid;
    int b = gid >> 6;
    int lane = gid & 63;
    if (b < B){
      const float* ab = adds + b * NQ;
      float cw[NQ], sw[NQ];
      #pragma unroll
      for (int w = 0; w < NQ; ++w)
        __sincosf(0.5f * ab[w], &sw[w], &cw[w]);
      float p6 = 1.f;
      #pragma unroll
      for (int w = 0; w < 6; ++w)
        p6 *= ((lane >> (5 - w)) & 1) ? sw[w] : cw[w];
      union { unsigned short u[8]; uint4 v; } pk;
      #pragma unroll
      for (int j = 0; j < 8; ++j){
        float p = p6 * (((j>>2)&1) ? sw[6] : cw[6])
                     * (((j>>1)&1) ? sw[7] : cw[7])
                     * (( j    &1) ? sw[8] : cw[8]);
        pk.u[j] = f2bf(p);
      }
      *(uint4*)(cT + (size_t)b * NS + lane*8) = pk.v;
    }
    if (gid < B) out[gid] = 0.f;
    return;
  }

  // ---- sim path ----
  __shared__ float2 ebufA[1024];   // [col][wvb][r][lane], ping
  __shared__ float2 ebufB[1024];   // pong
  __shared__ float scoef[COEF_FLOATS];

  // inline coefficient precompute into LDS (identical math to previous version)
  if (tid < 72){
    int blk = tid / 9, I = tid % 9;
    const float* p = (blk < 3) ? params + blk*36 : params2 + (blk-3)*36;
    float s0,c0,s1,c1,s2,c2,s3,c3;
    __sincosf(0.5f*p[4*I+0], &s0, &c0);
    __sincosf(0.5f*p[4*I+1], &s1, &c1);
    __sincosf(0.5f*p[4*I+2], &s2, &c2);
    __sincosf(0.5f*p[4*I+3], &s3, &c3);
    float m[4][4] = {
      { c0*c1, -c0*s1, -s0*c1,  s0*s1},
      { c0*s1,  c0*c1, -s0*s1, -s0*c1},
      { s0*c1, -s0*s1,  c0*c1, -c0*s1},
      { s0*s1,  s0*c1,  c0*s1,  c0*c1}};
    float gx[4][4], gy[4][4];
    #pragma unroll
    for (int q = 0; q < 4; ++q){
      gx[0][q] = m[1][q];  gy[0][q] = 0.f;      // row swap from X(q_target)
      gx[1][q] = m[0][q];  gy[1][q] = 0.f;
      gx[2][q] =  c3*c2*m[2][q] - s3*s2*m[3][q];
      gy[2][q] =  c3*s2*m[2][q] - s3*c2*m[3][q];
      gx[3][q] =  s3*s2*m[2][q] + c3*c2*m[3][q];
      gy[3][q] = -(s3*c2*m[2][q] + c3*s2*m[3][q]);
    }
    float* dst = scoef + tid*32;
    #pragma unroll
    for (int pp = 0; pp < 4; ++pp)
      #pragma unroll
      for (int d = 0; d < 4; ++d){
        dst[pp*4+d]    = gx[pp][pp^d];   // Hx[p][d] = Gx[p][p^d]
        dst[16+pp*4+d] = gy[pp][pp^d];
      }
  } else if (tid < 99){
    int r = tid - 72;
    int l = r / 9, i = r % 9;
    const float* w = weights + l*27 + 3*i;
    float phi = w[0], th = w[1], om = w[2];
    float sT,cT,sA,cA,sB,cB;
    __sincosf(0.5f*th, &sT, &cT);
    __sincosf(0.5f*(phi+om), &sA, &cA);
    __sincosf(0.5f*(om-phi), &sB, &cB);
    float* dst = scoef + COEF_ROT_BASE + r*8;
    dst[0] =  cA*cT;  dst[1] = -sA*cT;   // side 0: u00 (diag), u01 (off)
    dst[2] = -cB*sT;  dst[3] =  sB*sT;
    dst[4] =  cA*cT;  dst[5] =  sA*cT;   // side 1: u11 (diag), u10 (off)
    dst[6] =  cB*sT;  dst[7] =  sB*sT;
  } else if (tid < 123){
    // merged Rot(w0) x Rot(w1) x Rot(w2) tables: 24 threads = (layer l, row p)
    int idx = tid - 99;
    int l = idx >> 3, p = idx & 7;
    float e0x[3], e0y[3], e1x[3], e1y[3];
    #pragma unroll
    for (int w = 0; w < 3; ++w){
      const float* wp = weights + l*27 + 3*w;
      float phi = wp[0], th = wp[1], om = wp[2];
      float sT,cT,sA,cA,sB,cB;
      __sincosf(0.5f*th, &sT, &cT);
      __sincosf(0.5f*(phi+om), &sA, &cA);
      __sincosf(0.5f*(om-phi), &sB, &cB);
      int pw = (p >> (2 - w)) & 1;
      if (pw == 0){ e0x[w] =  cA*cT; e0y[w] = -sA*cT; e1x[w] = -cB*sT; e1y[w] =  sB*sT; }
      else        { e0x[w] =  cB*sT; e0y[w] =  sB*sT; e1x[w] =  cA*cT; e1y[w] =  sA*cT; }
    }
    float* dst = scoef + COEF_R3_BASE + l*128 + p*16;
    #pragma unroll
    for (int q = 0; q < 8; ++q){
      float rx = 1.f, ry = 0.f;
      #pragma unroll
      for (int w = 0; w < 3; ++w){
        int qw = (q >> (2 - w)) & 1;
        float fx = qw ? e1x[w] : e0x[w];
        float fy = qw ? e1y[w] : e0y[w];
        float nx = rx*fx - ry*fy;
        float ny = rx*fy + ry*fx;
        rx = nx; ry = ny;
      }
      dst[q*2]   = rx;
      dst[q*2+1] = ry;
    }
  }
  __syncthreads();

  int wid = tid >> 6, lane = tid & 63;
  int colbit = wid >> 1, wvb = wid & 1;
  int col = blockIdx.x * 2 + colbit;
  float2* ebA = ebufA + colbit * 512;
  float2* ebB = ebufB + colbit * 512;

  float ax[4], ay[4];
  int pc = __popc((unsigned)col) & 3;
  float prx = (pc==0) ? 1.f : (pc==2 ? -1.f : 0.f);
  float pry = (pc==3) ? 1.f : (pc==1 ? -1.f : 0.f);
  #pragma unroll
  for (int r = 0; r < 4; ++r){
    int i = (wvb<<8) | (r<<6) | lane;
    ax[r] = (i == col) ? prx : 0.f;
    ay[r] = (i == col) ? pry : 0.f;
  }

  #pragma unroll 1
  for (int blk = 0; blk < 3; ++blk)
    ent_blkQ<0>(ax, ay, wvb, lane, ebA, ebB, scoef + blk*288);

  rot3Q(ax, ay, wvb, lane, ebA, scoef + COEF_R3_BASE + 0*128);
  sel_rotsQ<3>(ax, ay, lane, scoef + COEF_ROT_BASE + 0*72);
  ring1(ax, ay, wvb, lane, ebB);
  rot3Q(ax, ay, wvb, lane, ebA, scoef + COEF_R3_BASE + 1*128);
  sel_rotsQ<3>(ax, ay, lane, scoef + COEF_ROT_BASE + 1*72);
  ring2(ax, ay, wvb, lane, ebB);
  rot3Q(ax, ay, wvb, lane, ebA, scoef + COEF_R3_BASE + 2*128);
  sel_rotsQ<3>(ax, ay, lane, scoef + COEF_ROT_BASE + 2*72);
  ring3(ax, ay, wvb, lane, ebB);

  #pragma unroll 1
  for (int blk = 3; blk < 8; ++blk)
    ent_blkQ<0>(ax, ay, wvb, lane, ebA, ebB, scoef + blk*288);

  // ---- coalesced A2 write: layout [kb=block][row 0..1023][j=col&1] as packed u32 ----
  float2* Lb = ebufA;   // round parity: A is free here
  #pragma unroll
  for (int r = 0; r < 4; ++r) Lb[(wid*4+r)*64 + lane] = make_float2(ax[r], ay[r]);
  __syncthreads();
  int part = wid >> 1;   // 0: Re rows, 1: Im rows
  int wb = wid & 1;      // amp wave-bit handled by this wave
  unsigned int* Aw = (unsigned int*)A2;
  #pragma unroll
  for (int r = 0; r < 4; ++r){
    float2 v0 = Lb[(wb*4+r)*64 + lane];        // column 2*bx   (waves 0,1)
    float2 v1 = Lb[((2+wb)*4+r)*64 + lane];    // column 2*bx+1 (waves 2,3)
    float a0 = part ? v0.y : v0.x;
    float a1 = part ? v1.y : v1.x;
    unsigned int pk = (unsigned)f2bf(a0) | ((unsigned)f2bf(a1) << 16);
    int row = (part<<9) + (wb<<8) + (r<<6) + lane;
    Aw[(size_t)blockIdx.x * 1024 + row] = pk;
  }
}

// Phi2 = A2(1024x512) @ c(512xB); out[b] = sum_row sign(row) * Phi2[row][b]^2,
// sign(row) = -1 iff (row & 256). A2 layout: [kb=t>>1][row][t&1] packed u32.
__global__ __launch_bounds__(256) void gemm_out(const unsigned short* __restrict__ A2,
                                                const unsigned short* __restrict__ cT,
                                                float* __restrict__ out){
  int bx = blockIdx.x;            // N tile (128 cols of b)
  int by = blockIdx.y;            // M tile (128 rows), 8 tiles
  int tid = threadIdx.x;
  int wave = tid >> 6, lane = tid & 63;
  int wy = wave >> 1, wx = wave & 1;
  int lane15 = lane & 15, quad = lane >> 4;
  int rowBase = by*128 + wy*64;
  int colBase = bx*128 + wx*64;
  const unsigned int* Aw = (const unsigned int*)A2;
  const short* Bp = (const short*)cT;   // [col][k]

  f32x4 acc[4][4];
  #pragma unroll
  for (int i = 0; i < 4; ++i)
    #pragma unroll
    for (int j = 0; j < 4; ++j)
      acc[i][j] = (f32x4){0.f, 0.f, 0.f, 0.f};

  #pragma unroll 4
  for (int k0 = 0; k0 < NS; k0 += 32){
    union { unsigned int w[4]; bf16x8 v; } au[4];
    bf16x8 b[4];
    int kb0 = (k0 >> 1) + (quad << 2);
    #pragma unroll
    for (int mi = 0; mi < 4; ++mi){
      int row = rowBase + mi*16 + lane15;
      #pragma unroll
      for (int d = 0; d < 4; ++d)
        au[mi].w[d] = Aw[(size_t)(kb0 + d)*1024 + row];
    }
    #pragma unroll
    for (int ni = 0; ni < 4; ++ni)
      b[ni] = *(const bf16x8*)(Bp + (size_t)(colBase + ni*16 + lane15)*NS + k0 + quad*8);
    #pragma unroll
    for (int mi = 0; mi < 4; ++mi)
      #pragma unroll
      for (int ni = 0; ni < 4; ++ni)
        acc[mi][ni] = __builtin_amdgcn_mfma_f32_16x16x32_bf16(au[mi].v, b[ni], acc[mi][ni], 0, 0, 0);
  }

  float sign = (by & 2) ? -1.f : 1.f;
  #pragma unroll
  for (int ni = 0; ni < 4; ++ni){
    float cs = 0.f;
    #pragma unroll
    for (int mi = 0; mi < 4; ++mi)
      #pragma unroll
      for (int r = 0; r < 4; ++r)
        cs += acc[mi][ni][r] * acc[mi][ni][r];
    cs += __shfl_xor(cs, 16);
    cs += __shfl_xor(cs, 32);
    if (quad == 0)
      atomicAdd(out + colBase + ni*16 + lane15, sign * cs);
  }
}

extern "C" void kernel_launch(void* const* d_in, const int* in_sizes, int n_in,
                              void* d_out, int out_size, void* d_ws, size_t ws_size,
                              hipStream_t stream) {
  const float* adds    = (const float*)d_in[0];
  const float* params  = (const float*)d_in[1];
  const float* weights = (const float*)d_in[2];
  const float* params2 = (const float*)d_in[3];
  float* out = (float*)d_out;
  int B = in_sizes[0] / NQ;   // 8192

  unsigned short* A2 = (unsigned short*)d_ws;        // 1024*512 bf16 = 1 MB (kb-blocked)
  unsigned short* cT = A2 + (size_t)M2 * NS;         // B*512 bf16 = 8 MB

  int prepBlocks = (B * 64 + 255) / 256;             // 2048
  hipLaunchKernelGGL(sim_prep, dim3(NSIMB + prepBlocks), dim3(256), 0, stream,
                     params, weights, params2, adds, A2, cT, out, B);
  hipLaunchKernelGGL(gemm_out, dim3(B / 128, 8), dim3(256), 0, stream, A2, cT, out);
}